// Round 7
// baseline (205.403 us; speedup 1.0000x reference)
//
#include <hip/hip_runtime.h>
#include <stdint.h>

#define S_LEN 4096
#define NH    16
#define HD    64
#define RSTR  (NH * HD)   // seq-row stride in floats

typedef __attribute__((ext_vector_type(8))) __bf16 bf16x8;
typedef __attribute__((ext_vector_type(4))) short short4v;
typedef __attribute__((ext_vector_type(4))) float floatx4;

union BF8 { unsigned short u[8]; unsigned d[4]; uint4 q; bf16x8 v; };
union BF4 { unsigned short u[4]; unsigned d[2]; short4v s; };

// pack two f32 -> bf16x2 (round-half-up) in one v_perm_b32
__device__ __forceinline__ unsigned pkbf(float a, float b) {
    unsigned ua = __builtin_bit_cast(unsigned, a) + 0x8000u;
    unsigned ub = __builtin_bit_cast(unsigned, b) + 0x8000u;
    return __builtin_amdgcn_perm(ub, ua, 0x07060302u);
}

__device__ __forceinline__ floatx4 mfma16(short4v a, short4v b, floatx4 c) {
#if __has_builtin(__builtin_amdgcn_mfma_f32_16x16x16bf16_1k)
    return __builtin_amdgcn_mfma_f32_16x16x16bf16_1k(a, b, c, 0, 0, 0);
#else
    floatx4 d;
    asm volatile("v_mfma_f32_16x16x16_bf16 %0, %1, %2, %3\n\ts_nop 7\n\ts_nop 7"
                 : "=v"(d) : "v"(a), "v"(b), "v"(c));
    return d;
#endif
}

__device__ __forceinline__ void gl16(const void* g, void* l) {
#if __has_builtin(__builtin_amdgcn_global_load_lds)
    __builtin_amdgcn_global_load_lds((const __attribute__((address_space(1))) unsigned int*)g,
                                     (__attribute__((address_space(3))) unsigned int*)l, 16, 0, 0);
#else
    *(uint4*)l = *(const uint4*)g;
#endif
}

// ---------------- preprocess: K -> bf16 swizzled tiles, V -> V^T bf16 swizzled tiles
// tile(h,tau) = 64x64 bf16 = 8 KB; element (r,c) at r*64 + ((c>>3)^(r&7))*8 + (c&7)
__global__ __launch_bounds__(256)
void pp_kv(const float* __restrict__ K, const float* __restrict__ V,
           unsigned short* __restrict__ Kz, unsigned short* __restrict__ Vz) {
    const int bid = blockIdx.x;
    const int h   = bid & 15;
    const int tau = bid >> 4;
    const int tid = threadIdx.x;
    {
        const int r = tid >> 2, gg = tid & 3;
        const float* kp = K + ((size_t)(64 * tau + r) * NH + h) * HD + 16 * gg;
        const float4 a = *reinterpret_cast<const float4*>(kp);
        const float4 b = *reinterpret_cast<const float4*>(kp + 4);
        const float4 c = *reinterpret_cast<const float4*>(kp + 8);
        const float4 d = *reinterpret_cast<const float4*>(kp + 12);
        uint4 f0, f1;
        f0.x = pkbf(a.x, a.y); f0.y = pkbf(a.z, a.w);
        f0.z = pkbf(b.x, b.y); f0.w = pkbf(b.z, b.w);
        f1.x = pkbf(c.x, c.y); f1.y = pkbf(c.z, c.w);
        f1.z = pkbf(d.x, d.y); f1.w = pkbf(d.z, d.w);
        unsigned short* out = Kz + ((size_t)(h * 64 + tau)) * 4096 + r * 64;
        *reinterpret_cast<uint4*>(out + (((2 * gg)     ^ (r & 7)) * 8)) = f0;
        *reinterpret_cast<uint4*>(out + (((2 * gg + 1) ^ (r & 7)) * 8)) = f1;
    }
    {
        const int dr = tid & 63, kg = tid >> 6;
        const float* vp = V + ((size_t)(64 * tau + 16 * kg) * NH + h) * HD + dr;
        float x[16];
        #pragma unroll
        for (int j = 0; j < 16; ++j) x[j] = vp[(size_t)j * RSTR];
        uint4 g0, g1;
        g0.x = pkbf(x[0],  x[1]);  g0.y = pkbf(x[2],  x[3]);
        g0.z = pkbf(x[4],  x[5]);  g0.w = pkbf(x[6],  x[7]);
        g1.x = pkbf(x[8],  x[9]);  g1.y = pkbf(x[10], x[11]);
        g1.z = pkbf(x[12], x[13]); g1.w = pkbf(x[14], x[15]);
        unsigned short* out = Vz + ((size_t)(h * 64 + tau)) * 4096 + dr * 64;
        *reinterpret_cast<uint4*>(out + (((2 * kg)     ^ (dr & 7)) * 8)) = g0;
        *reinterpret_cast<uint4*>(out + (((2 * kg + 1) ^ (dr & 7)) * 8)) = g1;
    }
}

// ---------------- main kernel: waves split kv; Q in registers; P in registers
__global__ __launch_bounds__(256, 4)
void fa_main(const float* __restrict__ Q, const unsigned short* __restrict__ Kz,
             const unsigned short* __restrict__ Vz, const int* __restrict__ causal_p,
             float* __restrict__ O) {
    __shared__ __align__(16) unsigned char smem[32768];
    unsigned short* Klds = (unsigned short*)smem;              // 2 x 8 KB dbuf
    unsigned short* Vlds = (unsigned short*)(smem + 16384);    // 2 x 8 KB dbuf
    float* Lsum = (float*)smem;                                // epilogue overlay (1 KB)
    float* Lred = (float*)(smem + 1024);                       // epilogue overlay (18.4 KB)

    const int bid = blockIdx.x;
    const int h   = bid & 15;
    const int s   = bid >> 4;
    const int jj  = s & 15;
    const int kk  = s >> 4;
    int x;                                 // balanced: CU's set {j,31-j,32+j,63-j}
    if (kk == 0) x = jj; else if (kk == 1) x = 31 - jj;
    else if (kk == 2) x = 32 + jj; else x = 63 - jj;
    const int q0 = x * 64;

    const int tid = threadIdx.x;
    const int wv  = tid >> 6;
    const int ln  = tid & 63;
    const int c16 = ln & 15;
    const int qd  = ln >> 4;
    const int causal = causal_p[0];

    const float SC = 0.18033688011112042f;  // (1/sqrt(64)) * log2(e)

    const int e7 = c16 & 7;
    const int o0 = (qd ^ e7) * 8;              // elems, x32 frag chunk 0
    const int o1 = ((4 + qd) ^ e7) * 8;        // elems, x32 frag chunk 1
    const int vo = ((2 * wv + (qd >> 1)) ^ e7) * 8 + (qd & 1) * 4;  // V^T b64 frag

    // glds pointers (per-lane; lane0 value is the wave-uniform LDS base)
    const char* kg = (const char*)Kz + (size_t)h * 64 * 8192 + wv * 2048 + ln * 16;
    const char* vg = (const char*)Vz + (size_t)h * 64 * 8192 + wv * 2048 + ln * 16;
    char* kl = (char*)smem + wv * 2048 + ln * 16;
    char* vl = (char*)smem + 16384 + wv * 2048 + ln * 16;

#define GLDS_TILE(TI, BUF) do {                                  \
    const char* ks_ = kg + (size_t)(TI) * 8192;                  \
    const char* vs_ = vg + (size_t)(TI) * 8192;                  \
    char* kd_ = kl + (BUF) * 8192;                               \
    char* vd_ = vl + (BUF) * 8192;                               \
    gl16(ks_, kd_); gl16(ks_ + 1024, kd_ + 1024);                \
    gl16(vs_, vd_); gl16(vs_ + 1024, vd_ + 1024);                \
} while (0)

    GLDS_TILE(0, 0);   // start tile 0 before Q register loads

    // ---- Q fragments in registers (B-operand layout), pre-scaled:
    // qf[t][c] elem j = Q[q0+16t+c16][32c+8qd+j] * SC ----
    BF8 qf[4][2];
    #pragma unroll
    for (int t = 0; t < 4; ++t) {
        const float* qp = Q + ((size_t)(q0 + 16 * t + c16) * NH + h) * HD + 8 * qd;
        #pragma unroll
        for (int c = 0; c < 2; ++c) {
            const float4 a = *reinterpret_cast<const float4*>(qp + 32 * c);
            const float4 b = *reinterpret_cast<const float4*>(qp + 32 * c + 4);
            qf[t][c].d[0] = pkbf(a.x * SC, a.y * SC);
            qf[t][c].d[1] = pkbf(a.z * SC, a.w * SC);
            qf[t][c].d[2] = pkbf(b.x * SC, b.y * SC);
            qf[t][c].d[3] = pkbf(b.z * SC, b.w * SC);
        }
    }

    BF4 ones;
    ones.d[0] = 0x3F803F80u; ones.d[1] = 0x3F803F80u;   // bf16 1.0 x4

    const int nIter = causal ? (x + 1) : (S_LEN / 64);

    floatx4 acc[4][4];   // [md][t] partial O^T over this wave's kv slice
    #pragma unroll
    for (int m = 0; m < 4; ++m)
        #pragma unroll
        for (int t = 0; t < 4; ++t) acc[m][t] = floatx4{0.f, 0.f, 0.f, 0.f};
    floatx4 lcc[4];      // per-t row-sum partials (all regs equal)
    #pragma unroll
    for (int t = 0; t < 4; ++t) lcc[t] = floatx4{0.f, 0.f, 0.f, 0.f};

    __syncthreads();

    int cur = 0;
    for (int it = 0; it < nIter; ++it) {
        if (it + 1 < nIter) GLDS_TILE(it + 1, cur ^ 1);

        const unsigned short* Kb = Klds + cur * 4096;
        const unsigned short* Vb = Vlds + cur * 4096;

        // K fragment: rows kv = 16wv + c16 (this wave's kv slice)
        const unsigned short* krow = Kb + (16 * wv + c16) * 64;
        const bf16x8 kf0 = *reinterpret_cast<const bf16x8*>(krow + o0);
        const bf16x8 kf1 = *reinterpret_cast<const bf16x8*>(krow + o1);

        const bool maskit = (causal != 0) && (it == nIter - 1);

        // S^T = K Q^T per q-tile t; exp2 -> P directly in B-layout for x16 PV
        BF4 pf[4];
        #pragma unroll
        for (int t = 0; t < 4; ++t) {
            floatx4 st = __builtin_amdgcn_mfma_f32_16x16x32_bf16(
                kf0, qf[t][0].v, floatx4{0.f, 0.f, 0.f, 0.f}, 0, 0, 0);
            st = __builtin_amdgcn_mfma_f32_16x16x32_bf16(kf1, qf[t][1].v, st, 0, 0, 0);
            const int D = 16 * t + c16 - 16 * wv - 4 * qd;   // mask i > D
            float p[4];
            #pragma unroll
            for (int i = 0; i < 4; ++i) {
                float sv = st[i];
                if (maskit && (i > D)) sv = -1e30f;
                p[i] = __builtin_amdgcn_exp2f(sv);
            }
            pf[t].d[0] = pkbf(p[0], p[1]);
            pf[t].d[1] = pkbf(p[2], p[3]);
            lcc[t] = mfma16(ones.s, pf[t].s, lcc[t]);   // l partial via MFMA
        }

        // O^T(partial) += V^T[:, kv_wv] P^T[kv_wv, :]  (x16, k=16)
        #pragma unroll
        for (int md = 0; md < 4; ++md) {
            BF4 vf;
            const unsigned short* vrow = Vb + (16 * md + c16) * 64 + vo;
            *reinterpret_cast<uint2*>(&vf.d[0]) = *reinterpret_cast<const uint2*>(vrow);
            #pragma unroll
            for (int t = 0; t < 4; ++t)
                acc[md][t] = mfma16(vf.s, pf[t].s, acc[md][t]);
        }

        __syncthreads();   // drains glds (next buf ready) + protects buf reuse
        cur ^= 1;
    }

    // ---- epilogue: cross-wave reduction of partial O^T and l via LDS ----
    // Lane (c16,qd) reg (md,t,i) holds O^T[d=16md+4qd+i][q=16t+c16].
    #pragma unroll
    for (int t = 0; t < 4; ++t)
        if (qd == 0) Lsum[wv * 64 + t * 16 + c16] = lcc[t][0];

    const int qi  = tid & 63;          // reader: owns q row q0+qi
    const int dg  = tid >> 6;          // reader: d sub-block
    const int lnr = 16 * dg + (qi & 15);
    const int jb  = 4 * (qi >> 4);
    float* orow = O + ((size_t)(q0 + qi) * NH + h) * HD;
    float inv = 0.f;

    for (int md = 0; md < 4; ++md) {
        float* Lw = Lred + (wv * 64 + ln) * 18;
        #pragma unroll
        for (int t = 0; t < 4; ++t) {
            float2 w0; w0.x = acc[md][t][0]; w0.y = acc[md][t][1];
            float2 w1; w1.x = acc[md][t][2]; w1.y = acc[md][t][3];
            *reinterpret_cast<float2*>(&Lw[4 * t])     = w0;
            *reinterpret_cast<float2*>(&Lw[4 * t + 2]) = w1;
        }
        __syncthreads();
        if (md == 0) {
            const float l = Lsum[qi] + Lsum[64 + qi] + Lsum[128 + qi] + Lsum[192 + qi];
            inv = 1.0f / l;
        }
        float s0 = 0.f, s1 = 0.f, s2 = 0.f, s3 = 0.f;
        #pragma unroll
        for (int w = 0; w < 4; ++w) {
            const float* Lr = Lred + (w * 64 + lnr) * 18 + jb;
            s0 += Lr[0]; s1 += Lr[1]; s2 += Lr[2]; s3 += Lr[3];
        }
        floatx4 o; o[0] = s0 * inv; o[1] = s1 * inv; o[2] = s2 * inv; o[3] = s3 * inv;
        *reinterpret_cast<floatx4*>(orow + 16 * md + 4 * dg) = o;
        __syncthreads();
    }
}

extern "C" void kernel_launch(void* const* d_in, const int* in_sizes, int n_in,
                              void* d_out, int out_size, void* d_ws, size_t ws_size,
                              hipStream_t stream) {
    const float* q = (const float*)d_in[0];
    const float* k = (const float*)d_in[1];
    const float* v = (const float*)d_in[2];
    const int* causal = (const int*)d_in[3];
    float* out = (float*)d_out;
    unsigned short* Kz = (unsigned short*)d_ws;                      // 8 MB
    unsigned short* Vz = Kz + (size_t)NH * 64 * 4096;                // 8 MB
    pp_kv<<<dim3(64 * NH), dim3(256), 0, stream>>>(k, v, Kz, Vz);
    fa_main<<<dim3(64 * NH), dim3(256), 0, stream>>>(q, Kz, Vz, causal, out);
}